// Round 15
// baseline (106.312 us; speedup 1.0000x reference)
//
#include <hip/hip_runtime.h>
#include <math.h>

typedef __attribute__((ext_vector_type(8))) short bf16x8;
typedef __attribute__((ext_vector_type(4))) short bf16x4;
typedef __attribute__((ext_vector_type(4))) float f32x4;
typedef __attribute__((ext_vector_type(2))) unsigned int u32x2;

static constexpr int D_MODEL = 1024;
static constexpr int SEQ = 2048;
static constexpr int BATCH = 2;
static constexpr int M_TOT = BATCH * SEQ;   // 4096

__device__ __forceinline__ unsigned short f2bf(float f) {
  unsigned int u = __builtin_bit_cast(unsigned int, f);
  u += 0x7fffu + ((u >> 16) & 1u);   // round-to-nearest-even
  return (unsigned short)(u >> 16);
}

// pack 2 fp32 -> 2 bf16 in one instr (no builtin on gfx950; RNE)
__device__ __forceinline__ unsigned int cvtpk(float lo, float hi) {
  unsigned int r;
  asm volatile("v_cvt_pk_bf16_f32 %0, %1, %2" : "=v"(r) : "v"(lo), "v"(hi));
  return r;
}

// async global -> LDS, 16B per lane.  LDS dst = wave-uniform base + lane*16.
// GLOBAL src is PER-LANE — caller must include the lane offset.
__device__ __forceinline__ void gld16(const unsigned short* g, unsigned short* l) {
  __builtin_amdgcn_global_load_lds(
      (const __attribute__((address_space(1))) unsigned int*)g,
      (__attribute__((address_space(3))) unsigned int*)l, 16, 0, 0);
}

// ---------------- prep: fp32 -> bf16 (vectorized) ----------------
__global__ void cvt_f32_bf16(const float* __restrict__ src,
                             unsigned short* __restrict__ dst, int n4) {
  int i = blockIdx.x * blockDim.x + threadIdx.x;
  if (i >= n4) return;
  const float4 v = reinterpret_cast<const float4*>(src)[i];
  ushort4 o;
  o.x = f2bf(v.x); o.y = f2bf(v.y); o.z = f2bf(v.z); o.w = f2bf(v.w);
  reinterpret_cast<ushort4*>(dst)[i] = o;
}

// all 4 weights in one dispatch; dst regions are contiguous (Wq|Wk|Wv|Wo).
__global__ void cvt_weights(const float* __restrict__ qw, const float* __restrict__ kw,
                            const float* __restrict__ vw, const float* __restrict__ ow,
                            unsigned short* __restrict__ dst) {
  int i = blockIdx.x * blockDim.x + threadIdx.x;   // over 4 * 2^18 float4 groups
  const int which = i >> 18;
  const int off = i & 262143;
  const float* src = (which == 0) ? qw : (which == 1) ? kw : (which == 2) ? vw : ow;
  const float4 v = reinterpret_cast<const float4*>(src)[off];
  ushort4 o;
  o.x = f2bf(v.x); o.y = f2bf(v.y); o.z = f2bf(v.z); o.w = f2bf(v.w);
  reinterpret_cast<ushort4*>(dst)[i] = o;
}

// ---------------- prep: interleaved RoPE table [SEQ][32] float2, bank-swizzled ----------------
__global__ void rope_tables(float2* __restrict__ ct2) {
  int idx = blockIdx.x * blockDim.x + threadIdx.x;   // SEQ*32
  int s = idx >> 5;
  int p = idx & 31;
  float inv_freq = powf(10000.0f, -(float)p / 32.0f);
  float ang = (float)s * inv_freq;
  int psw = p ^ (((s >> 2) & 1) << 3);
  float2 cs; cs.x = cosf(ang); cs.y = sinf(ang);
  ct2[s * 32 + psw] = cs;
}

// ---------------- GEMM v3 (round-12 proven, unchanged) ----------------
template <int BM, int BN, int MODE>
__global__ __launch_bounds__(256, 2)
void gemm2(const unsigned short* __restrict__ A,
           const unsigned short* __restrict__ W,
           unsigned short* __restrict__ Qd,
           unsigned short* __restrict__ Kd,
           unsigned short* __restrict__ Vd,
           float* __restrict__ Fd,
           const float2* __restrict__ ct2) {
  constexpr int MI = BM / 32, NI = BN / 32;
  constexpr int NKT = D_MODEL / 32;            // 32 k-steps
  constexpr int LOADS = BM / 64 + BN / 64;     // gld16 per wave per stage
  __shared__ __align__(16) unsigned short smem[2 * (BM + BN) * 32];  // 32KB @128x128
  unsigned short* Asm = smem;                  // [2][BM*32]
  unsigned short* Bsm = smem + 2 * BM * 32;    // [2][BN*32]
  const int tid  = threadIdx.x;
  const int lane = tid & 63;
  const int wave = tid >> 6;
  const int wm = wave >> 1, wn = wave & 1;
  const int m0 = blockIdx.y * BM;
  const int n0 = blockIdx.x * BN;
  const int lr = lane & 15, lg = lane >> 4;

  const int srow = lane >> 2;
  const int scol = ((lane & 3) ^ ((lane >> 3) & 3)) * 8;

  auto stage = [&](int buf, int kt) {
    const int k0 = kt * 32;
#pragma unroll
    for (int rr = 0; rr < BM / 64; ++rr) {
      const int ch = rr * 4 + wave;
      gld16(&A[(size_t)(m0 + ch * 16 + srow) * D_MODEL + k0 + scol], &Asm[buf * BM * 32 + ch * 512]);
    }
#pragma unroll
    for (int rr = 0; rr < BN / 64; ++rr) {
      const int ch = rr * 4 + wave;
      gld16(&W[(size_t)(n0 + ch * 16 + srow) * D_MODEL + k0 + scol], &Bsm[buf * BN * 32 + ch * 512]);
    }
  };

  f32x4 acc[MI][NI] = {};

  stage(0, 0);
  stage(1, 1);
  __builtin_amdgcn_sched_barrier(0);

  const int swz = (lg ^ ((lr >> 1) & 3)) * 8;  // frag-read chunk swizzle

  for (int kt = 0; kt < NKT; ++kt) {
    const int cur = kt & 1;
    if (kt + 1 < NKT) {
      if constexpr (LOADS == 4) asm volatile("s_waitcnt vmcnt(4)" ::: "memory");
      else                      asm volatile("s_waitcnt vmcnt(3)" ::: "memory");
    } else {
      asm volatile("s_waitcnt vmcnt(0)" ::: "memory");
    }
    __builtin_amdgcn_s_barrier();
    __builtin_amdgcn_sched_barrier(0);

    bf16x8 af[MI], bfr[NI];
#pragma unroll
    for (int i = 0; i < MI; ++i)
      af[i] = *reinterpret_cast<const bf16x8*>(&Asm[cur * BM * 32 + (wm * (BM / 2) + i * 16 + lr) * 32 + swz]);
#pragma unroll
    for (int j = 0; j < NI; ++j)
      bfr[j] = *reinterpret_cast<const bf16x8*>(&Bsm[cur * BN * 32 + (wn * (BN / 2) + j * 16 + lr) * 32 + swz]);
    asm volatile("s_waitcnt lgkmcnt(0)" ::: "memory");
    __builtin_amdgcn_sched_barrier(0);
    __builtin_amdgcn_s_barrier();            // all waves done reading buf cur
    __builtin_amdgcn_sched_barrier(0);

    if (kt + 2 < NKT) stage(cur, kt + 2);
    __builtin_amdgcn_sched_barrier(0);

#pragma unroll
    for (int i = 0; i < MI; ++i)
#pragma unroll
      for (int j = 0; j < NI; ++j)
        acc[i][j] = __builtin_amdgcn_mfma_f32_16x16x32_bf16(af[i], bfr[j], acc[i][j], 0, 0, 0);
  }
  // loop's final read-complete s_barrier has synced all waves; smem is dead.

  if constexpr (MODE == 2) {
#pragma unroll
    for (int i = 0; i < MI; ++i)
#pragma unroll
      for (int j = 0; j < NI; ++j)
#pragma unroll
        for (int r = 0; r < 4; ++r) {
          const int gm = m0 + wm * (BM / 2) + i * 16 + lg * 4 + r;
          const int gc = n0 + wn * (BN / 2) + j * 16 + lr;
          Fd[(size_t)gm * D_MODEL + gc] = acc[i][j][r];
        }
  } else {
    const int t = n0 >> 10;                    // uniform per block
    const int b = m0 >> 11;
    const int s_base = m0 & 2047;
    if (t < 2) {
      // ---- Q/K: RoPE via LDS table ----
      unsigned short* dstQ = (t == 0) ? Qd : Kd;
      const unsigned short* gsrc = (const unsigned short*)(ct2 + (size_t)s_base * 32);
#pragma unroll
      for (int it = 0; it < 8; ++it) {
        const int ch = wave * 8 + it;
        gld16(&gsrc[ch * 512 + lane * 8], &smem[ch * 512]);
      }
      asm volatile("s_waitcnt vmcnt(0)" ::: "memory");
      __builtin_amdgcn_sched_barrier(0);
      __builtin_amdgcn_s_barrier();
      const float2* tbl = (const float2*)smem;
      const int nbase = (n0 & 1023) >> 6;
#pragma unroll
      for (int i = 0; i < MI; ++i) {
#pragma unroll
        for (int j = 0; j < NI; ++j) {
#pragma unroll
          for (int r = 0; r < 4; ++r) {
            const int sl = wm * (BM / 2) + i * 16 + lg * 4 + r;   // s_local 0..127
            const int h  = j * 16 + lr;                            // 0..63
            const int psw = (h >> 1) ^ (((sl >> 2) & 1) << 3);
            const float2 cs = tbl[sl * 32 + psw];
            float x = acc[i][j][r];
            const float part = __shfl_xor(x, 1, 64);
            x = (h & 1) ? (part * cs.y + x * cs.x) : (x * cs.x - part * cs.y);
            const int n = nbase + wn;
            dstQ[(size_t)((b * 16 + n) * SEQ + s_base + sl) * 64 + h] = f2bf(x);
          }
        }
      }
    } else {
      // ---- V: transpose via LDS, coalesced [bn][h][s] stores ----
      unsigned short* tile = smem;             // [64 cols][136]
      const int row = tid >> 2;                // 0..63
      const int ck  = tid & 3;
      for (int pass = 0; pass < 2; ++pass) {
        __builtin_amdgcn_s_barrier();
        if (wn == pass) {
#pragma unroll
          for (int i = 0; i < MI; ++i)
#pragma unroll
            for (int j = 0; j < NI; ++j)
#pragma unroll
              for (int r = 0; r < 4; ++r)
                tile[(j * 16 + lr) * 136 + wm * 64 + i * 16 + lg * 4 + r] = f2bf(acc[i][j][r]);
        }
        asm volatile("s_waitcnt lgkmcnt(0)" ::: "memory");
        __builtin_amdgcn_sched_barrier(0);
        __builtin_amdgcn_s_barrier();
        const int c = (n0 & 1023) + pass * 64 + row;
        const int n = c >> 6, h = c & 63;
        unsigned short* vrow = &Vd[(size_t)((b * 16 + n) * 64 + h) * SEQ + s_base + ck * 32];
        const unsigned short* lrow = &tile[row * 136 + ck * 32];
#pragma unroll
        for (int k = 0; k < 4; ++k)
          *reinterpret_cast<bf16x8*>(&vrow[k * 8]) = *reinterpret_cast<const bf16x8*>(&lrow[k * 8]);
      }
    }
  }
}

// ---------------- flash attention v12: KVBLK=128, P in registers ----------------
// One tile = 128 k: K[128][64] + V[64][128] staged once (8 gld16/wave, vmcnt(8)),
// body = two sequential 64-k sub-chains (round-14 register pattern; sub-chain 0's
// regs die before sub-chain 1's live).  Barriers/waits/stage calls per unit work
// halve.  V rows (256B stride) XOR-swizzled on 16B chunks by (h&15) -> 2-way reads.
__global__ __launch_bounds__(256, 2)
void attn_kernel(const unsigned short* __restrict__ Q,
                 const unsigned short* __restrict__ K,
                 const unsigned short* __restrict__ Vt,
                 unsigned short* __restrict__ AO) {
  __shared__ __align__(16) unsigned short Ksh[2][8192];  // [buf][128 x 64] swizzled
  __shared__ __align__(16) unsigned short Vsh[2][8192];  // [buf][64 x 128] swizzled
  const int bn   = blockIdx.x;
  const int j    = (gridDim.y - 1) - blockIdx.y;   // heavy-first
  const int wave = threadIdx.x >> 6;
  const int lane = threadIdx.x & 63;
  const int lr = lane & 15, lg = lane >> 4;
  const int q0 = j * 128 + wave * 32;
  const unsigned short* Qh = Q  + (size_t)bn * SEQ * 64;
  const unsigned short* Kh = K  + (size_t)bn * SEQ * 64;
  const unsigned short* Vh = Vt + (size_t)bn * 64 * SEQ;
  const int b = bn >> 4, n = bn & 15;

  auto stage = [&](int buf, int k0) {
#pragma unroll
    for (int c = 0; c < 4; ++c) {              // K: 16 chunks of 8 rows x 64
      const int ch = wave * 4 + c;
      const int row = ch * 8 + (lane >> 3);
      gld16(&Kh[(size_t)(k0 + row) * 64 + ((lane & 7) ^ (row & 7)) * 8], &Ksh[buf][ch * 512]);
    }
#pragma unroll
    for (int c = 0; c < 4; ++c) {              // V: 16 chunks of 4 rows x 128
      const int ch = wave * 4 + c;
      const int row = ch * 4 + (lane >> 4);
      gld16(&Vh[(size_t)row * SEQ + k0 + ((lane & 15) ^ (row & 15)) * 8], &Vsh[buf][ch * 512]);
    }
  };

  constexpr float KL2E = 0.125f * 1.44269504088896f;
  const int nt = j + 1;                        // causal k-tiles of 128

  bf16x8 qf[2][2];
#pragma unroll
  for (int mi = 0; mi < 2; ++mi)
#pragma unroll
    for (int ks = 0; ks < 2; ++ks)
      qf[mi][ks] = *reinterpret_cast<const bf16x8*>(
          &Qh[(size_t)(q0 + mi * 16 + lr) * 64 + ks * 32 + lg * 8]);
  asm volatile("s_waitcnt vmcnt(0)" ::: "memory");  // clean slate for counted waits
  __builtin_amdgcn_sched_barrier(0);

  f32x4 o[2][4] = {};
  float ls[2] = {0.f, 0.f};                    // row-sum for q = mi*16+lr (in-lane k)

  stage(0, 0);
  stage(1, 128);
  __builtin_amdgcn_sched_barrier(0);

  for (int t = 0; t < nt; ++t) {
    const int cur = t & 1;
    if (t + 1 < nt) { asm volatile("s_waitcnt vmcnt(8)" ::: "memory"); }
    else            { asm volatile("s_waitcnt vmcnt(0)" ::: "memory"); }
    __builtin_amdgcn_s_barrier();            // all waves' stage(t) visible
    __builtin_amdgcn_sched_barrier(0);

    const unsigned short* Kc = &Ksh[cur][0];
    const unsigned short* Vc = &Vsh[cur][0];

#pragma unroll
    for (int kh = 0; kh < 2; ++kh) {
      const int k0h = t * 128 + kh * 64;

      // ---- K frags (XOR-swizzled read) + swapped QK^T ----
      bf16x8 kf[4][2];
#pragma unroll
      for (int nj = 0; nj < 4; ++nj)
#pragma unroll
        for (int ks = 0; ks < 2; ++ks) {
          const int R = kh * 64 + nj * 16 + lr;
          const int p = (ks * 4 + lg) ^ (R & 7);
          kf[nj][ks] = *reinterpret_cast<const bf16x8*>(&Kc[R * 64 + p * 8]);
        }
      f32x4 sf[2][4] = {};   // sf[mi][nj][r] = S[q=q0+mi*16+lr][k=k0h+nj*16+lg*4+r]
      __builtin_amdgcn_s_setprio(1);
#pragma unroll
      for (int nj = 0; nj < 4; ++nj)
#pragma unroll
        for (int ks = 0; ks < 2; ++ks)
#pragma unroll
          for (int mi = 0; mi < 2; ++mi)
            sf[mi][nj] = __builtin_amdgcn_mfma_f32_16x16x32_bf16(kf[nj][ks], qf[mi][ks], sf[mi][nj], 0, 0, 0);
      __builtin_amdgcn_s_setprio(0);

      // ---- V B-frags (b64: 4 consecutive s at row h) — latency hides under exp ----
      bf16x4 vB[4][4];   // [nj][hf]: V[k0h+nj*16+lg*4+{0..3}][hf*16+lr]
#pragma unroll
      for (int nj = 0; nj < 4; ++nj)
#pragma unroll
        for (int hf = 0; hf < 4; ++hf) {
          const int R = hf * 16 + lr;
          const int c0 = kh * 8 + nj * 2 + (lg >> 1);
          const int p = ((c0 ^ (R & 15)) << 3) + (lg & 1) * 4;
          vB[nj][hf] = *reinterpret_cast<const bf16x4*>(&Vc[R * 128 + p]);
        }

      // ---- exp + pack(bf16x2) into registers (no LDS) ----
      u32x2 w[2][4];     // w[mi][nj] = P[q=lr][k=nj*16+lg*4+{0..3}] packed bf16
      if (k0h + 63 <= q0) {                    // fully unmasked (wave-uniform)
#pragma unroll
        for (int mi = 0; mi < 2; ++mi)
#pragma unroll
          for (int nj = 0; nj < 4; ++nj) {
            const float p0 = __builtin_amdgcn_exp2f(sf[mi][nj][0] * KL2E);
            const float p1 = __builtin_amdgcn_exp2f(sf[mi][nj][1] * KL2E);
            const float p2 = __builtin_amdgcn_exp2f(sf[mi][nj][2] * KL2E);
            const float p3 = __builtin_amdgcn_exp2f(sf[mi][nj][3] * KL2E);
            ls[mi] += (p0 + p1) + (p2 + p3);
            w[mi][nj][0] = cvtpk(p0, p1);
            w[mi][nj][1] = cvtpk(p2, p3);
          }
      } else {
#pragma unroll
        for (int mi = 0; mi < 2; ++mi) {
          const int qrow = q0 + mi * 16 + lr;
#pragma unroll
          for (int nj = 0; nj < 4; ++nj) {
            const int kb = k0h + nj * 16 + lg * 4;
            float p[4];
#pragma unroll
            for (int r = 0; r < 4; ++r)
              p[r] = (kb + r <= qrow) ? __builtin_amdgcn_exp2f(sf[mi][nj][r] * KL2E) : 0.0f;
            ls[mi] += (p[0] + p[1]) + (p[2] + p[3]);
            w[mi][nj][0] = cvtpk(p[0], p[1]);
            w[mi][nj][1] = cvtpk(p[2], p[3]);
          }
        }
      }

      // ---- PV: pure-register 16x16x16 MFMA (A = packed P, B = vB) ----
      __builtin_amdgcn_s_setprio(1);
#pragma unroll
      for (int nj = 0; nj < 4; ++nj)
#pragma unroll
        for (int hf = 0; hf < 4; ++hf)
#pragma unroll
          for (int mi = 0; mi < 2; ++mi)
            o[mi][hf] = __builtin_amdgcn_mfma_f32_16x16x16bf16_1k(
                __builtin_bit_cast(bf16x4, w[mi][nj]), vB[nj][hf], o[mi][hf], 0, 0, 0);
      __builtin_amdgcn_s_setprio(0);
    }

    asm volatile("s_waitcnt lgkmcnt(0)" ::: "memory");   // all LDS reads of buf cur done
    __builtin_amdgcn_sched_barrier(0);
    __builtin_amdgcn_s_barrier();            // all waves done reading buf cur
    __builtin_amdgcn_sched_barrier(0);

    if (t + 2 < nt) stage(cur, (t + 2) * 128);   // lands during next tile's body
    __builtin_amdgcn_sched_barrier(0);
  }

  // ---- final reduce: lanes sharing lr hold partial sums for q=mi*16+lr ----
#pragma unroll
  for (int mi = 0; mi < 2; ++mi) {
    float s = ls[mi];
    s += __shfl_xor(s, 16, 64);
    s += __shfl_xor(s, 32, 64);
    ls[mi] = s;
  }
#pragma unroll
  for (int mi = 0; mi < 2; ++mi)
#pragma unroll
    for (int r = 0; r < 4; ++r) {
      const float sv = __shfl(ls[mi], lg * 4 + r, 64);   // lane lg*4+r holds q=mi*16+lg*4+r
      const float inv = 1.0f / sv;
      const int srow = q0 + mi * 16 + lg * 4 + r;
#pragma unroll
      for (int hf = 0; hf < 4; ++hf) {
        const int h = hf * 16 + lr;
        AO[(size_t)(b * SEQ + srow) * D_MODEL + n * 64 + h] = f2bf(o[mi][hf][r] * inv);
      }
    }
}

// ---------------- launch ----------------
extern "C" void kernel_launch(void* const* d_in, const int* in_sizes, int n_in,
                              void* d_out, int out_size, void* d_ws, size_t ws_size,
                              hipStream_t stream) {
  const float* qw = (const float*)d_in[0];
  const float* kw = (const float*)d_in[1];
  const float* vw = (const float*)d_in[2];
  const float* ow = (const float*)d_in[3];
  const float* x  = (const float*)d_in[4];

  char* ws = (char*)d_ws;
  const size_t XB = (size_t)M_TOT * D_MODEL * 2;      // 8 MB
  const size_t WB = (size_t)D_MODEL * D_MODEL * 2;    // 2 MB
  unsigned short* Xb  = (unsigned short*)ws;  ws += XB;
  unsigned short* Wqb = (unsigned short*)ws;  ws += WB;  // Wq|Wk|Wv|Wo contiguous
  unsigned short* Wkb = (unsigned short*)ws;  ws += WB;
  unsigned short* Wvb = (unsigned short*)ws;  ws += WB;
  unsigned short* Wob = (unsigned short*)ws;  ws += WB;
  unsigned short* Qr  = (unsigned short*)ws;  ws += XB;
  unsigned short* Kr  = (unsigned short*)ws;  ws += XB;
  unsigned short* Vt  = (unsigned short*)ws;  ws += XB;
  unsigned short* AO  = (unsigned short*)ws;  ws += XB;
  float2* ct2 = (float2*)ws;  ws += (size_t)SEQ * 32 * 8;   // interleaved rope table
  (void)Wkb; (void)Wvb;

  cvt_f32_bf16<<<(M_TOT * D_MODEL / 4) / 256, 256, 0, stream>>>(x, Xb, M_TOT * D_MODEL / 4);
  cvt_weights<<<(4 * D_MODEL * D_MODEL / 4) / 256, 256, 0, stream>>>(qw, kw, vw, ow, Wqb);
  rope_tables<<<(SEQ * 32) / 256, 256, 0, stream>>>(ct2);

  // merged QKV projection: N = 3072
  gemm2<128, 128, 0><<<dim3(3072 / 128, M_TOT / 128), 256, 0, stream>>>(
      Xb, Wqb, Qr, Kr, Vt, nullptr, ct2);

  attn_kernel<<<dim3(BATCH * 16, 16), 256, 0, stream>>>(Qr, Kr, Vt, AO);

  // final projection: N = 1024, 128x64 tile -> 512 blocks
  gemm2<128, 64, 2><<<dim3(D_MODEL / 64, M_TOT / 128), 256, 0, stream>>>(
      AO, Wob, nullptr, nullptr, nullptr, (float*)d_out, nullptr);
}

// Round 16
// 102.124 us; speedup vs baseline: 1.0410x; 1.0410x over previous
//
#include <hip/hip_runtime.h>
#include <math.h>

typedef __attribute__((ext_vector_type(8))) short bf16x8;
typedef __attribute__((ext_vector_type(4))) short bf16x4;
typedef __attribute__((ext_vector_type(4))) float f32x4;
typedef __attribute__((ext_vector_type(2))) unsigned int u32x2;

static constexpr int D_MODEL = 1024;
static constexpr int SEQ = 2048;
static constexpr int BATCH = 2;
static constexpr int M_TOT = BATCH * SEQ;   // 4096

__device__ __forceinline__ unsigned short f2bf(float f) {
  unsigned int u = __builtin_bit_cast(unsigned int, f);
  u += 0x7fffu + ((u >> 16) & 1u);   // round-to-nearest-even
  return (unsigned short)(u >> 16);
}

// pack 2 fp32 -> 2 bf16 in one instr (no builtin on gfx950; RNE)
__device__ __forceinline__ unsigned int cvtpk(float lo, float hi) {
  unsigned int r;
  asm volatile("v_cvt_pk_bf16_f32 %0, %1, %2" : "=v"(r) : "v"(lo), "v"(hi));
  return r;
}

// async global -> LDS, 16B per lane.  LDS dst = wave-uniform base + lane*16.
// GLOBAL src is PER-LANE — caller must include the lane offset.
__device__ __forceinline__ void gld16(const unsigned short* g, unsigned short* l) {
  __builtin_amdgcn_global_load_lds(
      (const __attribute__((address_space(1))) unsigned int*)g,
      (__attribute__((address_space(3))) unsigned int*)l, 16, 0, 0);
}

// ---------------- prep: fp32 -> bf16 (vectorized) ----------------
__global__ void cvt_f32_bf16(const float* __restrict__ src,
                             unsigned short* __restrict__ dst, int n4) {
  int i = blockIdx.x * blockDim.x + threadIdx.x;
  if (i >= n4) return;
  const float4 v = reinterpret_cast<const float4*>(src)[i];
  ushort4 o;
  o.x = f2bf(v.x); o.y = f2bf(v.y); o.z = f2bf(v.z); o.w = f2bf(v.w);
  reinterpret_cast<ushort4*>(dst)[i] = o;
}

// all 4 weights in one dispatch; dst regions are contiguous (Wq|Wk|Wv|Wo).
__global__ void cvt_weights(const float* __restrict__ qw, const float* __restrict__ kw,
                            const float* __restrict__ vw, const float* __restrict__ ow,
                            unsigned short* __restrict__ dst) {
  int i = blockIdx.x * blockDim.x + threadIdx.x;   // over 4 * 2^18 float4 groups
  const int which = i >> 18;
  const int off = i & 262143;
  const float* src = (which == 0) ? qw : (which == 1) ? kw : (which == 2) ? vw : ow;
  const float4 v = reinterpret_cast<const float4*>(src)[off];
  ushort4 o;
  o.x = f2bf(v.x); o.y = f2bf(v.y); o.z = f2bf(v.z); o.w = f2bf(v.w);
  reinterpret_cast<ushort4*>(dst)[i] = o;
}

// ---------------- prep: interleaved RoPE table [SEQ][32] float2, bank-swizzled ----------------
__global__ void rope_tables(float2* __restrict__ ct2) {
  int idx = blockIdx.x * blockDim.x + threadIdx.x;   // SEQ*32
  int s = idx >> 5;
  int p = idx & 31;
  float inv_freq = powf(10000.0f, -(float)p / 32.0f);
  float ang = (float)s * inv_freq;
  int psw = p ^ (((s >> 2) & 1) << 3);
  float2 cs; cs.x = cosf(ang); cs.y = sinf(ang);
  ct2[s * 32 + psw] = cs;
}

// ---------------- GEMM v5: BK=64, counted-vmcnt k-loop, fast epilogue ----------------
// Halves sync points vs BK=32 (16 k-steps, 2 barriers each), doubles MFMA per
// barrier-pair.  LDS tile [ROWS][64] swizzled: 16B chunk c stored at c ^ (row&7)
// (attn-K pattern, 2-way conflict-free).  Epilogues unchanged (round-11 proven).
template <int BM, int BN, int MODE>
__global__ __launch_bounds__(256, 2)
void gemm2(const unsigned short* __restrict__ A,
           const unsigned short* __restrict__ W,
           unsigned short* __restrict__ Qd,
           unsigned short* __restrict__ Kd,
           unsigned short* __restrict__ Vd,
           float* __restrict__ Fd,
           const float2* __restrict__ ct2) {
  constexpr int MI = BM / 32, NI = BN / 32;
  constexpr int NKT = D_MODEL / 64;            // 16 k-steps (BK=64)
  constexpr int LOADS = BM / 32 + BN / 32;     // gld16 per wave per stage
  __shared__ __align__(16) unsigned short smem[2 * (BM + BN) * 64];
  unsigned short* Asm = smem;                  // [2][BM*64]
  unsigned short* Bsm = smem + 2 * BM * 64;    // [2][BN*64]
  const int tid  = threadIdx.x;
  const int lane = tid & 63;
  const int wave = tid >> 6;
  const int wm = wave >> 1, wn = wave & 1;
  const int m0 = blockIdx.y * BM;
  const int n0 = blockIdx.x * BN;
  const int lr = lane & 15, lg = lane >> 4;

  // stage: chunk = 8 rows x 64 cols (1KB); source col chunk pre-swizzled by row&7.
  auto stage = [&](int buf, int kt) {
    const int k0 = kt * 64;
#pragma unroll
    for (int c = 0; c < BM / 32; ++c) {
      const int ch = c * 4 + wave;
      const int row = ch * 8 + (lane >> 3);
      gld16(&A[(size_t)(m0 + row) * D_MODEL + k0 + ((lane & 7) ^ (row & 7)) * 8],
            &Asm[buf * BM * 64 + ch * 512]);
    }
#pragma unroll
    for (int c = 0; c < BN / 32; ++c) {
      const int ch = c * 4 + wave;
      const int row = ch * 8 + (lane >> 3);
      gld16(&W[(size_t)(n0 + row) * D_MODEL + k0 + ((lane & 7) ^ (row & 7)) * 8],
            &Bsm[buf * BN * 64 + ch * 512]);
    }
  };

  f32x4 acc[MI][NI] = {};

  stage(0, 0);
  stage(1, 1);
  __builtin_amdgcn_sched_barrier(0);

  for (int kt = 0; kt < NKT; ++kt) {
    const int cur = kt & 1;
    if (kt + 1 < NKT) {
      if constexpr (LOADS == 8) asm volatile("s_waitcnt vmcnt(8)" ::: "memory");
      else                      asm volatile("s_waitcnt vmcnt(6)" ::: "memory");
    } else {
      asm volatile("s_waitcnt vmcnt(0)" ::: "memory");
    }
    __builtin_amdgcn_s_barrier();
    __builtin_amdgcn_sched_barrier(0);

    bf16x8 af[MI][2], bfr[NI][2];
#pragma unroll
    for (int i = 0; i < MI; ++i)
#pragma unroll
      for (int ks = 0; ks < 2; ++ks) {
        const int R = wm * (BM / 2) + i * 16 + lr;
        const int p = (ks * 4 + lg) ^ (R & 7);
        af[i][ks] = *reinterpret_cast<const bf16x8*>(&Asm[cur * BM * 64 + R * 64 + p * 8]);
      }
#pragma unroll
    for (int j = 0; j < NI; ++j)
#pragma unroll
      for (int ks = 0; ks < 2; ++ks) {
        const int R = wn * (BN / 2) + j * 16 + lr;
        const int p = (ks * 4 + lg) ^ (R & 7);
        bfr[j][ks] = *reinterpret_cast<const bf16x8*>(&Bsm[cur * BN * 64 + R * 64 + p * 8]);
      }
    asm volatile("s_waitcnt lgkmcnt(0)" ::: "memory");
    __builtin_amdgcn_sched_barrier(0);
    __builtin_amdgcn_s_barrier();            // all waves done reading buf cur
    __builtin_amdgcn_sched_barrier(0);

    if (kt + 2 < NKT) stage(cur, kt + 2);
    __builtin_amdgcn_sched_barrier(0);

#pragma unroll
    for (int ks = 0; ks < 2; ++ks)
#pragma unroll
      for (int i = 0; i < MI; ++i)
#pragma unroll
        for (int j = 0; j < NI; ++j)
          acc[i][j] = __builtin_amdgcn_mfma_f32_16x16x32_bf16(af[i][ks], bfr[j][ks], acc[i][j], 0, 0, 0);
  }
  // loop's final read-complete s_barrier has synced all waves; smem is dead.

  if constexpr (MODE == 2) {
#pragma unroll
    for (int i = 0; i < MI; ++i)
#pragma unroll
      for (int j = 0; j < NI; ++j)
#pragma unroll
        for (int r = 0; r < 4; ++r) {
          const int gm = m0 + wm * (BM / 2) + i * 16 + lg * 4 + r;
          const int gc = n0 + wn * (BN / 2) + j * 16 + lr;
          Fd[(size_t)gm * D_MODEL + gc] = acc[i][j][r];
        }
  } else {
    const int t = n0 >> 10;                    // uniform per block
    const int b = m0 >> 11;
    const int s_base = m0 & 2047;
    if (t < 2) {
      // ---- Q/K: RoPE via LDS table ----
      unsigned short* dstQ = (t == 0) ? Qd : Kd;
      const unsigned short* gsrc = (const unsigned short*)(ct2 + (size_t)s_base * 32);
#pragma unroll
      for (int it = 0; it < 8; ++it) {
        const int ch = wave * 8 + it;
        gld16(&gsrc[ch * 512 + lane * 8], &smem[ch * 512]);
      }
      asm volatile("s_waitcnt vmcnt(0)" ::: "memory");
      __builtin_amdgcn_sched_barrier(0);
      __builtin_amdgcn_s_barrier();
      const float2* tbl = (const float2*)smem;
      const int nbase = (n0 & 1023) >> 6;
#pragma unroll
      for (int i = 0; i < MI; ++i) {
#pragma unroll
        for (int j = 0; j < NI; ++j) {
#pragma unroll
          for (int r = 0; r < 4; ++r) {
            const int sl = wm * (BM / 2) + i * 16 + lg * 4 + r;   // s_local 0..127
            const int h  = j * 16 + lr;                            // 0..63
            const int psw = (h >> 1) ^ (((sl >> 2) & 1) << 3);
            const float2 cs = tbl[sl * 32 + psw];
            float x = acc[i][j][r];
            const float part = __shfl_xor(x, 1, 64);
            x = (h & 1) ? (part * cs.y + x * cs.x) : (x * cs.x - part * cs.y);
            const int n = nbase + wn;
            dstQ[(size_t)((b * 16 + n) * SEQ + s_base + sl) * 64 + h] = f2bf(x);
          }
        }
      }
    } else {
      // ---- V: transpose via LDS, coalesced [bn][h][s] stores ----
      unsigned short* tile = smem;             // [64 cols][136]
      const int row = tid >> 2;                // 0..63
      const int ck  = tid & 3;
      for (int pass = 0; pass < 2; ++pass) {
        __builtin_amdgcn_s_barrier();
        if (wn == pass) {
#pragma unroll
          for (int i = 0; i < MI; ++i)
#pragma unroll
            for (int j = 0; j < NI; ++j)
#pragma unroll
              for (int r = 0; r < 4; ++r)
                tile[(j * 16 + lr) * 136 + wm * 64 + i * 16 + lg * 4 + r] = f2bf(acc[i][j][r]);
        }
        asm volatile("s_waitcnt lgkmcnt(0)" ::: "memory");
        __builtin_amdgcn_sched_barrier(0);
        __builtin_amdgcn_s_barrier();
        const int c = (n0 & 1023) + pass * 64 + row;
        const int n = c >> 6, h = c & 63;
        unsigned short* vrow = &Vd[(size_t)((b * 16 + n) * 64 + h) * SEQ + s_base + ck * 32];
        const unsigned short* lrow = &tile[row * 136 + ck * 32];
#pragma unroll
        for (int k = 0; k < 4; ++k)
          *reinterpret_cast<bf16x8*>(&vrow[k * 8]) = *reinterpret_cast<const bf16x8*>(&lrow[k * 8]);
      }
    }
  }
}

// ---------------- flash attention v13: round-14 core + complementary pair dispatch ----------------
// j-map: y<8 -> 15-y (heavy half first), y>=8 -> y-8.  Co-resident pair (block i,
// i+256) = same bn, j pair (15-y, y) -> nt sum = 34 tiles on EVERY CU (was 48..20).
// Core: KVBLK=64, swapped QK^T, cvt_pk P kept in registers (A-frag of 16x16x16),
// counted vmcnt(4), raw barriers, block-shared swizzled LDS K/V.
__global__ __launch_bounds__(256, 2)
void attn_kernel(const unsigned short* __restrict__ Q,
                 const unsigned short* __restrict__ K,
                 const unsigned short* __restrict__ Vt,
                 unsigned short* __restrict__ AO) {
  __shared__ __align__(16) unsigned short Ksh[2][4096];  // [buf][64 x 64] swizzled
  __shared__ __align__(16) unsigned short Vsh[2][4096];
  const int bn   = blockIdx.x;
  const int y    = blockIdx.y;
  const int j    = (y < 8) ? (15 - y) : (y - 8);   // complementary pairing
  const int wave = threadIdx.x >> 6;
  const int lane = threadIdx.x & 63;
  const int lr = lane & 15, lg = lane >> 4;
  const int q0 = j * 128 + wave * 32;
  const unsigned short* Qh = Q  + (size_t)bn * SEQ * 64;
  const unsigned short* Kh = K  + (size_t)bn * SEQ * 64;
  const unsigned short* Vh = Vt + (size_t)bn * 64 * SEQ;
  const int b = bn >> 4, n = bn & 15;

  const int srow8 = lane >> 3;
  const int scolb = ((lane & 7) ^ srow8) * 8;

  auto stage = [&](int buf, int k0) {
#pragma unroll
    for (int c = 0; c < 2; ++c) {
      const int ch = wave * 2 + c;
      const int row = ch * 8 + srow8;
      gld16(&Kh[(size_t)(k0 + row) * 64 + scolb], &Ksh[buf][ch * 512]);
      gld16(&Vh[(size_t)row * SEQ + k0 + scolb], &Vsh[buf][ch * 512]);
    }
  };

  constexpr float KL2E = 0.125f * 1.44269504088896f;
  const int nt = 2 * j + 2;

  bf16x8 qf[2][2];
#pragma unroll
  for (int mi = 0; mi < 2; ++mi)
#pragma unroll
    for (int ks = 0; ks < 2; ++ks)
      qf[mi][ks] = *reinterpret_cast<const bf16x8*>(
          &Qh[(size_t)(q0 + mi * 16 + lr) * 64 + ks * 32 + lg * 8]);
  asm volatile("s_waitcnt vmcnt(0)" ::: "memory");
  __builtin_amdgcn_sched_barrier(0);

  f32x4 o[2][4] = {};
  float ls[2] = {0.f, 0.f};                    // row-sum for q = mi*16+lr (in-lane k)

  stage(0, 0);
  stage(1, 64);
  __builtin_amdgcn_sched_barrier(0);

  for (int t = 0; t < nt; ++t) {
    const int cur = t & 1;
    const int k0 = t * 64;
    if (t + 1 < nt) { asm volatile("s_waitcnt vmcnt(4)" ::: "memory"); }
    else            { asm volatile("s_waitcnt vmcnt(0)" ::: "memory"); }
    __builtin_amdgcn_s_barrier();            // all waves' stage(t) visible
    __builtin_amdgcn_sched_barrier(0);

    const unsigned short* Kc = &Ksh[cur][0];
    const unsigned short* Vc = &Vsh[cur][0];

    // ---- K frags (XOR-swizzled read) + swapped QK^T ----
    bf16x8 kf[4][2];
#pragma unroll
    for (int nj = 0; nj < 4; ++nj)
#pragma unroll
      for (int ks = 0; ks < 2; ++ks) {
        const int R = nj * 16 + lr;
        const int p = (ks * 4 + lg) ^ (R & 7);
        kf[nj][ks] = *reinterpret_cast<const bf16x8*>(&Kc[R * 64 + p * 8]);
      }
    f32x4 sf[2][4] = {};   // sf[mi][nj][r] = S[q=q0+mi*16+lr][k=k0+nj*16+lg*4+r]
    __builtin_amdgcn_s_setprio(1);
#pragma unroll
    for (int nj = 0; nj < 4; ++nj)
#pragma unroll
      for (int ks = 0; ks < 2; ++ks)
#pragma unroll
        for (int mi = 0; mi < 2; ++mi)
          sf[mi][nj] = __builtin_amdgcn_mfma_f32_16x16x32_bf16(kf[nj][ks], qf[mi][ks], sf[mi][nj], 0, 0, 0);
    __builtin_amdgcn_s_setprio(0);

    // ---- V B-frags (b64: 4 consecutive s at row h) — latency hides under exp ----
    bf16x4 vB[4][4];   // [nj][hf]: V[k0+nj*16+lg*4+{0..3}][hf*16+lr]
#pragma unroll
    for (int nj = 0; nj < 4; ++nj)
#pragma unroll
      for (int hf = 0; hf < 4; ++hf) {
        const int R = hf * 16 + lr;
        const int c = nj * 2 + (lg >> 1);
        const int p = ((c ^ (R & 7)) << 3) + (lg & 1) * 4;
        vB[nj][hf] = *reinterpret_cast<const bf16x4*>(&Vc[R * 64 + p]);
      }

    // ---- exp + pack(bf16x2) into registers (no LDS) ----
    u32x2 w[2][4];     // w[mi][nj] = P[q=lr][k=nj*16+lg*4+{0..3}] packed bf16
    if (k0 + 63 <= q0) {                       // fully unmasked (wave-uniform)
#pragma unroll
      for (int mi = 0; mi < 2; ++mi)
#pragma unroll
        for (int nj = 0; nj < 4; ++nj) {
          const float p0 = __builtin_amdgcn_exp2f(sf[mi][nj][0] * KL2E);
          const float p1 = __builtin_amdgcn_exp2f(sf[mi][nj][1] * KL2E);
          const float p2 = __builtin_amdgcn_exp2f(sf[mi][nj][2] * KL2E);
          const float p3 = __builtin_amdgcn_exp2f(sf[mi][nj][3] * KL2E);
          ls[mi] += (p0 + p1) + (p2 + p3);
          w[mi][nj][0] = cvtpk(p0, p1);
          w[mi][nj][1] = cvtpk(p2, p3);
        }
    } else {
#pragma unroll
      for (int mi = 0; mi < 2; ++mi) {
        const int qrow = q0 + mi * 16 + lr;
#pragma unroll
        for (int nj = 0; nj < 4; ++nj) {
          const int kb = k0 + nj * 16 + lg * 4;
          float p[4];
#pragma unroll
          for (int r = 0; r < 4; ++r)
            p[r] = (kb + r <= qrow) ? __builtin_amdgcn_exp2f(sf[mi][nj][r] * KL2E) : 0.0f;
          ls[mi] += (p[0] + p[1]) + (p[2] + p[3]);
          w[mi][nj][0] = cvtpk(p[0], p[1]);
          w[mi][nj][1] = cvtpk(p[2], p[3]);
        }
      }
    }

    asm volatile("s_waitcnt lgkmcnt(0)" ::: "memory");   // kf + vB reads done
    __builtin_amdgcn_sched_barrier(0);
    __builtin_amdgcn_s_barrier();            // all waves done reading buf cur
    __builtin_amdgcn_sched_barrier(0);

    if (t + 2 < nt) stage(cur, (t + 2) * 64);
    __builtin_amdgcn_sched_barrier(0);

    // ---- PV: pure-register 16x16x16 MFMA (A = packed P, B = vB) ----
    __builtin_amdgcn_s_setprio(1);
#pragma unroll
    for (int nj = 0; nj < 4; ++nj)
#pragma unroll
      for (int hf = 0; hf < 4; ++hf)
#pragma unroll
        for (int mi = 0; mi < 2; ++mi)
          o[mi][hf] = __builtin_amdgcn_mfma_f32_16x16x16bf16_1k(
              __builtin_bit_cast(bf16x4, w[mi][nj]), vB[nj][hf], o[mi][hf], 0, 0, 0);
    __builtin_amdgcn_s_setprio(0);
  }

  // ---- final reduce: lanes sharing lr hold partial sums for q=mi*16+lr ----
#pragma unroll
  for (int mi = 0; mi < 2; ++mi) {
    float s = ls[mi];
    s += __shfl_xor(s, 16, 64);
    s += __shfl_xor(s, 32, 64);
    ls[mi] = s;
  }
#pragma unroll
  for (int mi = 0; mi < 2; ++mi)
#pragma unroll
    for (int r = 0; r < 4; ++r) {
      const float sv = __shfl(ls[mi], lg * 4 + r, 64);   // lane lg*4+r holds q=mi*16+lg*4+r
      const float inv = 1.0f / sv;
      const int srow = q0 + mi * 16 + lg * 4 + r;
#pragma unroll
      for (int hf = 0; hf < 4; ++hf) {
        const int h = hf * 16 + lr;
        AO[(size_t)(b * SEQ + srow) * D_MODEL + n * 64 + h] = f2bf(o[mi][hf][r] * inv);
      }
    }
}

// ---------------- launch ----------------
extern "C" void kernel_launch(void* const* d_in, const int* in_sizes, int n_in,
                              void* d_out, int out_size, void* d_ws, size_t ws_size,
                              hipStream_t stream) {
  const float* qw = (const float*)d_in[0];
  const float* kw = (const float*)d_in[1];
  const float* vw = (const float*)d_in[2];
  const float* ow = (const float*)d_in[3];
  const float* x  = (const float*)d_in[4];

  char* ws = (char*)d_ws;
  const size_t XB = (size_t)M_TOT * D_MODEL * 2;      // 8 MB
  const size_t WB = (size_t)D_MODEL * D_MODEL * 2;    // 2 MB
  unsigned short* Xb  = (unsigned short*)ws;  ws += XB;
  unsigned short* Wqb = (unsigned short*)ws;  ws += WB;  // Wq|Wk|Wv|Wo contiguous
  unsigned short* Wkb = (unsigned short*)ws;  ws += WB;
  unsigned short* Wvb = (unsigned short*)ws;  ws += WB;
  unsigned short* Wob = (unsigned short*)ws;  ws += WB;
  unsigned short* Qr  = (unsigned short*)ws;  ws += XB;
  unsigned short* Kr  = (unsigned short*)ws;  ws += XB;
  unsigned short* Vt  = (unsigned short*)ws;  ws += XB;
  unsigned short* AO  = (unsigned short*)ws;  ws += XB;
  float2* ct2 = (float2*)ws;  ws += (size_t)SEQ * 32 * 8;   // interleaved rope table
  (void)Wkb; (void)Wvb;

  cvt_f32_bf16<<<(M_TOT * D_MODEL / 4) / 256, 256, 0, stream>>>(x, Xb, M_TOT * D_MODEL / 4);
  cvt_weights<<<(4 * D_MODEL * D_MODEL / 4) / 256, 256, 0, stream>>>(qw, kw, vw, ow, Wqb);
  rope_tables<<<(SEQ * 32) / 256, 256, 0, stream>>>(ct2);

  // merged QKV projection: N = 3072
  gemm2<128, 128, 0><<<dim3(3072 / 128, M_TOT / 128), 256, 0, stream>>>(
      Xb, Wqb, Qr, Kr, Vt, nullptr, ct2);

  attn_kernel<<<dim3(BATCH * 16, 16), 256, 0, stream>>>(Qr, Kr, Vt, AO);

  // final projection: N = 1024, 128x64 tile -> 512 blocks
  gemm2<128, 64, 2><<<dim3(D_MODEL / 64, M_TOT / 128), 256, 0, stream>>>(
      AO, Wob, nullptr, nullptr, nullptr, (float*)d_out, nullptr);
}